// Round 18
// baseline (151.691 us; speedup 1.0000x reference)
//
#include <hip/hip_runtime.h>

typedef short bf16x8 __attribute__((ext_vector_type(8)));
typedef float f32x4 __attribute__((ext_vector_type(4)));
typedef float f32x16 __attribute__((ext_vector_type(16)));
typedef float float4v __attribute__((ext_vector_type(4)));
typedef short short4v __attribute__((ext_vector_type(4)));
typedef unsigned uint2v __attribute__((ext_vector_type(2)));
typedef unsigned uint4v __attribute__((ext_vector_type(4)));

#define B_ 4
#define S_ 2048
#define E_ 1024
#define H_ 16
#define D_ 64
#define M_ (B_*S_)      // 8192
#define N1_ (3*E_)      // 3072

__device__ inline short f2bs(float f) {
    unsigned u = __builtin_bit_cast(unsigned, f);
    unsigned r = u + 0x7fffu + ((u >> 16) & 1u);
    return (short)(r >> 16);
}
__device__ inline float exp2a(float x) {
    float r; asm("v_exp_f32 %0, %1" : "=v"(r) : "v"(x)); return r;
}
__device__ inline unsigned cvtpk(float a, float b) {
    unsigned r; asm("v_cvt_pk_bf16_f32 %0, %1, %2" : "=v"(r) : "v"(a), "v"(b)); return r;
}

__device__ inline const __attribute__((address_space(1))) void* gas(const void* p) {
    return (const __attribute__((address_space(1))) void*)p;
}
__device__ inline __attribute__((address_space(3))) void* las(void* p) {
    return (__attribute__((address_space(3))) void*)p;
}

// ---------------- fused prologue (R16 verified) ----------------
__global__ __launch_bounds__(256) void prologue(
    const float* __restrict__ x, short* __restrict__ Xbf,
    const float* __restrict__ w_attn, short* __restrict__ Wat,
    const float* __restrict__ w_out, short* __restrict__ Wot) {
    __shared__ float t[32][33];
    const int bid = blockIdx.x;
    const int tid = threadIdx.x;
    if (bid < 2048) {
        const int n = M_ * E_;
        const int stride = 2048 * 256 * 4;
        for (int i = (bid * 256 + tid) * 4; i < n; i += stride) {
            float4v v = *(const float4v*)&x[i];
            short4v o;
            o[0] = f2bs(v[0]); o[1] = f2bs(v[1]); o[2] = f2bs(v[2]); o[3] = f2bs(v[3]);
            *(short4v*)&Xbf[i] = o;
        }
    } else {
        const float* in;
        short* out;
        int rows, cols, bx, by;
        if (bid < 5120) {
            in = w_attn; out = Wat; rows = E_; cols = N1_;
            int b2 = bid - 2048;
            bx = (b2 % 96) * 32; by = (b2 / 96) * 32;
        } else {
            in = w_out; out = Wot; rows = E_; cols = E_;
            int b2 = bid - 5120;
            bx = (b2 & 31) * 32; by = (b2 >> 5) * 32;
        }
        const int tx = tid & 31, ty = tid >> 5;
#pragma unroll
        for (int i = 0; i < 4; ++i)
            t[ty + i * 8][tx] = in[(size_t)(by + ty + i * 8) * cols + bx + tx];
        __syncthreads();
#pragma unroll
        for (int i = 0; i < 4; ++i)
            out[(size_t)(bx + ty + i * 8) * rows + by + tx] = f2bs(t[tx][ty + i * 8]);
    }
}

#define VMW(n) asm volatile("s_waitcnt vmcnt(" #n ")" ::: "memory")
#define NOP_ ((void)0)

// ================= 128x192 GEMM (QKV), 2 merged phases/tile, 2 blocks/CU =================
#define QKV_MFMA1(Q, AF) \
    _Pragma("unroll") for (int nf = 0; nf < 6; ++nf) { \
        acc[(Q)][nf] = __builtin_amdgcn_mfma_f32_16x16x32_bf16(AF[0], bfrag[nf][0], acc[(Q)][nf], 0, 0, 0); \
        acc[(Q)][nf] = __builtin_amdgcn_mfma_f32_16x16x32_bf16(AF[1], bfrag[nf][1], acc[(Q)][nf], 0, 0, 0); \
    }

#define QKV_PHASE2(QA, STAGE_STMT, WAITV) do { \
    bf16x8 afA[2], afB[2]; \
    const char* lA0 = lA + (QA) * 4096; \
    const char* lA1 = lA + ((QA) + 1) * 4096; \
    _Pragma("unroll") for (int ks = 0; ks < 2; ++ks) { \
        afA[ks] = *(const bf16x8*)(lA0 + li * 128 + ((ks * 64 + g * 16) ^ ((li & 7) << 4))); \
        afB[ks] = *(const bf16x8*)(lA1 + li * 128 + ((ks * 64 + g * 16) ^ ((li & 7) << 4))); \
    } \
    STAGE_STMT; \
    __builtin_amdgcn_s_barrier(); \
    asm volatile("s_waitcnt lgkmcnt(0)" ::: "memory"); \
    __builtin_amdgcn_sched_barrier(0); \
    __builtin_amdgcn_s_setprio(1); \
    QKV_MFMA1(QA, afA); \
    QKV_MFMA1((QA) + 1, afB); \
    __builtin_amdgcn_s_setprio(0); \
    WAITV; \
    __builtin_amdgcn_s_barrier(); \
} while (0)

__global__ __launch_bounds__(256, 2) void gemm_qkv(
    const short* __restrict__ A, const short* __restrict__ Bt,
    const float* __restrict__ bias,
    short* __restrict__ Qb, short* __restrict__ Kb, short* __restrict__ Vt) {
    __shared__ __attribute__((aligned(16))) short ldsA[2][8192];   // [buf][4 calls][2 wr][16r][64k]
    __shared__ __attribute__((aligned(16))) short ldsB[2][12288];  // [buf][192r][64k]
    const int tid = threadIdx.x;
    const int lane = tid & 63;
    const int wid = tid >> 6;
    const int li = lane & 15, g = lane >> 4;
    const int wr = wid >> 1, wc = wid & 1;
    const int Kdim = E_;
    const int NT = Kdim >> 6;  // 16

    const int id = blockIdx.x;
    const int swz = (id & 7) * 128 + (id >> 3);
    const int bx = swz & 15, by = swz >> 4;
    const int row0 = by * 128, col0 = bx * 192;

    const int lr8 = lane >> 3;
    const int cstage = (((lane & 7) ^ (lr8 & 7)) << 4);

    auto stageA = [&](int buf, int kt) {
#pragma unroll
        for (int Q = 0; Q < 4; ++Q) {
            int grow = (wid >> 1) * 64 + Q * 16 + (wid & 1) * 8 + lr8;
            const char* src = (const char*)A +
                ((size_t)(row0 + grow) * Kdim + kt * 64) * 2 + cstage;
            char* dst = (char*)&ldsA[buf][0] + Q * 4096 + wid * 1024;
            __builtin_amdgcn_global_load_lds(gas(src), las(dst), 16, 0, 0);
        }
    };
    auto stageB = [&](int buf, int kt) {
#pragma unroll
        for (int i = 0; i < 6; ++i) {
            int grow = i * 32 + wid * 8 + lr8;
            const char* src = (const char*)Bt +
                ((size_t)(col0 + grow) * Kdim + kt * 64) * 2 + cstage;
            char* dst = (char*)&ldsB[buf][0] + i * 4096 + wid * 1024;
            __builtin_amdgcn_global_load_lds(gas(src), las(dst), 16, 0, 0);
        }
    };

    f32x4 acc[4][6];
#pragma unroll
    for (int m = 0; m < 4; ++m)
#pragma unroll
        for (int n = 0; n < 6; ++n) acc[m][n] = (f32x4){0.f, 0.f, 0.f, 0.f};

    stageB(0, 0);
    stageA(0, 0);
    asm volatile("s_waitcnt vmcnt(0)" ::: "memory");
    __syncthreads();

    for (int t = 0; t < NT; ++t) {
        const int cur = t & 1;
        const int nb = cur ^ 1;
        const int tn = t + 1;
        const bool st = (tn < NT);
        const char* lA = (const char*)&ldsA[cur][0] + wr * 2048;
        const char* lB = (const char*)&ldsB[cur][0];

        bf16x8 bfrag[6][2];
#pragma unroll
        for (int nf = 0; nf < 6; ++nf)
#pragma unroll
            for (int ks = 0; ks < 2; ++ks) {
                int r = wc * 96 + nf * 16 + li;
                bfrag[nf][ks] = *(const bf16x8*)(lB + r * 128 + ((ks * 64 + g * 16) ^ ((r & 7) << 4)));
            }
        if (st) {
            QKV_PHASE2(0, stageB(nb, tn), VMW(6));
            QKV_PHASE2(2, stageA(nb, tn), VMW(2));
        } else {
            QKV_PHASE2(0, NOP_, VMW(0));
            QKV_PHASE2(2, NOP_, NOP_);
        }
    }

    // ---- epilogue ----
#pragma unroll
    for (int nf = 0; nf < 6; ++nf) {
        int ncolg = col0 + wc * 96 + nf * 16 + li;
        float bv = bias[ncolg];
        int part = ncolg >> 10;
        int rem = ncolg & 1023;
        if (part < 2) {
            short* Dst = (part == 0) ? Qb : Kb;
#pragma unroll
            for (int mi = 0; mi < 4; ++mi) {
                int rbase = row0 + wr * 64 + mi * 16 + 4 * g;
#pragma unroll
                for (int j = 0; j < 4; ++j)
                    Dst[(size_t)(rbase + j) * E_ + rem] = f2bs(acc[mi][nf][j] + bv);
            }
        } else {
            int h = rem >> 6, d = rem & 63;
#pragma unroll
            for (int mi = 0; mi < 4; ++mi) {
                int s0 = row0 + wr * 64 + mi * 16 + 4 * g;
                int bb2 = s0 >> 11;
                int ss = s0 & 2047;
                uint2v p;
                p[0] = cvtpk(acc[mi][nf][0] + bv, acc[mi][nf][1] + bv);
                p[1] = cvtpk(acc[mi][nf][2] + bv, acc[mi][nf][3] + bv);
                *(uint2v*)&Vt[((size_t)(bb2 * H_ + h) * D_ + d) * S_ + ss] = p;
            }
        }
    }
}

// ================= 128x128 GEMM (out-proj), 2 merged phases/tile, 2 blocks/CU =================
#define OUT_MFMA1(Q, AF) \
    _Pragma("unroll") for (int nf = 0; nf < 4; ++nf) { \
        acc[(Q)][nf] = __builtin_amdgcn_mfma_f32_16x16x32_bf16(AF[0], bfrag[nf][0], acc[(Q)][nf], 0, 0, 0); \
        acc[(Q)][nf] = __builtin_amdgcn_mfma_f32_16x16x32_bf16(AF[1], bfrag[nf][1], acc[(Q)][nf], 0, 0, 0); \
    }

#define OUT_PHASE2(QA, STAGE_STMT, WAITV) do { \
    bf16x8 afA[2], afB[2]; \
    const char* lA0 = lA + (QA) * 4096; \
    const char* lA1 = lA + ((QA) + 1) * 4096; \
    _Pragma("unroll") for (int ks = 0; ks < 2; ++ks) { \
        afA[ks] = *(const bf16x8*)(lA0 + li * 128 + ((ks * 64 + g * 16) ^ ((li & 7) << 4))); \
        afB[ks] = *(const bf16x8*)(lA1 + li * 128 + ((ks * 64 + g * 16) ^ ((li & 7) << 4))); \
    } \
    STAGE_STMT; \
    __builtin_amdgcn_s_barrier(); \
    asm volatile("s_waitcnt lgkmcnt(0)" ::: "memory"); \
    __builtin_amdgcn_sched_barrier(0); \
    __builtin_amdgcn_s_setprio(1); \
    OUT_MFMA1(QA, afA); \
    OUT_MFMA1((QA) + 1, afB); \
    __builtin_amdgcn_s_setprio(0); \
    WAITV; \
    __builtin_amdgcn_s_barrier(); \
} while (0)

__global__ __launch_bounds__(256, 2) void gemm_out(
    const short* __restrict__ A, const short* __restrict__ Bt,
    const float* __restrict__ bias, float* __restrict__ Cf) {
    __shared__ __attribute__((aligned(16))) short ldsA[2][8192];
    __shared__ __attribute__((aligned(16))) short ldsB[2][8192];
    const int tid = threadIdx.x;
    const int lane = tid & 63;
    const int wid = tid >> 6;
    const int li = lane & 15, g = lane >> 4;
    const int wr = wid >> 1, wc = wid & 1;
    const int Kdim = E_;
    const int NT = Kdim >> 6;  // 16

    const int id = blockIdx.x;
    const int swz = (id & 7) * 64 + (id >> 3);
    const int bx = swz & 7, by = swz >> 3;
    const int row0 = by * 128, col0 = bx * 128;

    const int lr8 = lane >> 3;
    const int cstage = (((lane & 7) ^ (lr8 & 7)) << 4);

    auto stageA = [&](int buf, int kt) {
#pragma unroll
        for (int Q = 0; Q < 4; ++Q) {
            int grow = (wid >> 1) * 64 + Q * 16 + (wid & 1) * 8 + lr8;
            const char* src = (const char*)A +
                ((size_t)(row0 + grow) * Kdim + kt * 64) * 2 + cstage;
            char* dst = (char*)&ldsA[buf][0] + Q * 4096 + wid * 1024;
            __builtin_amdgcn_global_load_lds(gas(src), las(dst), 16, 0, 0);
        }
    };
    auto stageB = [&](int buf, int kt) {
#pragma unroll
        for (int i = 0; i < 4; ++i) {
            int grow = i * 32 + wid * 8 + lr8;
            const char* src = (const char*)Bt +
                ((size_t)(col0 + grow) * Kdim + kt * 64) * 2 + cstage;
            char* dst = (char*)&ldsB[buf][0] + i * 4096 + wid * 1024;
            __builtin_amdgcn_global_load_lds(gas(src), las(dst), 16, 0, 0);
        }
    };

    f32x4 acc[4][4];
#pragma unroll
    for (int m = 0; m < 4; ++m)
#pragma unroll
        for (int n = 0; n < 4; ++n) acc[m][n] = (f32x4){0.f, 0.f, 0.f, 0.f};

    stageB(0, 0);
    stageA(0, 0);
    asm volatile("s_waitcnt vmcnt(0)" ::: "memory");
    __syncthreads();

    for (int t = 0; t < NT; ++t) {
        const int cur = t & 1;
        const int nb = cur ^ 1;
        const int tn = t + 1;
        const bool st = (tn < NT);
        const char* lA = (const char*)&ldsA[cur][0] + wr * 2048;
        const char* lB = (const char*)&ldsB[cur][0];

        bf16x8 bfrag[4][2];
#pragma unroll
        for (int nf = 0; nf < 4; ++nf)
#pragma unroll
            for (int ks = 0; ks < 2; ++ks) {
                int r = wc * 64 + nf * 16 + li;
                bfrag[nf][ks] = *(const bf16x8*)(lB + r * 128 + ((ks * 64 + g * 16) ^ ((r & 7) << 4)));
            }
        if (st) {
            OUT_PHASE2(0, stageB(nb, tn), VMW(4));
            OUT_PHASE2(2, stageA(nb, tn), VMW(2));
        } else {
            OUT_PHASE2(0, NOP_, VMW(0));
            OUT_PHASE2(2, NOP_, NOP_);
        }
    }

#pragma unroll
    for (int nf = 0; nf < 4; ++nf) {
        int ncol = col0 + wc * 64 + nf * 16 + li;
        float bv = bias[ncol];
#pragma unroll
        for (int mi = 0; mi < 4; ++mi) {
            int rbase = row0 + wr * 64 + mi * 16 + 4 * g;
#pragma unroll
            for (int j = 0; j < 4; ++j)
                Cf[(size_t)(rbase + j) * E_ + ncol] = acc[mi][nf][j] + bv;
        }
    }
}

// ---------------- causal flash attention v10: counted-vmcnt K/V double-buffer ----------------
// Per tile: issue stage(t+1 -> buf^1) FIRST, then VMW(4) (waits own stage(t) only,
// never drains the prefetch), s_barrier (joins all waves' stage(t)), compute(buf),
// lgkmcnt(0)+s_barrier (all reads of buf done before t+1 overwrites buf^1... and
// before t+2 overwrites buf). Stage latency hides under compute(t) -- the R6 dbuf
// failed because __syncthreads' implicit vmcnt(0) drained the prefetch too.
#define GRP 1040
__global__ __launch_bounds__(256, 4) void attn_kernel(
    const short* __restrict__ Qb, const short* __restrict__ Kb,
    const short* __restrict__ Vt, short* __restrict__ Ob) {
    __shared__ __attribute__((aligned(16))) char Kl[2][8 * GRP];
    __shared__ __attribute__((aligned(16))) char Vl[2][8 * GRP];
    const int lane = threadIdx.x & 63;
    const int wv = threadIdx.x >> 6;
    const int l31 = lane & 31;
    const int hi = lane >> 5;
    const int id = blockIdx.x;
    const int xcd = id & 7;
    const int r_ = id >> 3;
    const int qt = 15 - (r_ >> 3);
    const int bh = xcd * 8 + (r_ & 7);
    const int bb = bh >> 4, hh = bh & 15;
    const short* Qh = Qb + (size_t)bb * (S_ * E_) + hh * 64;
    const short* Kh = Kb + (size_t)bb * (S_ * E_) + hh * 64;
    const short* Vh = Vt + (size_t)bh * (D_ * S_);
    const float CEXP = 0.18033688011112042f;

    const int rstage = wv * 8 + (lane >> 3);
    const int cstage = (((lane & 7) ^ ((lane >> 3) & 7)) << 4);

    const int q0w = qt * 128 + wv * 32;
    const int q = q0w + l31;

    bf16x8 qf[4];
#pragma unroll
    for (int c = 0; c < 4; ++c)
        qf[c] = *(const bf16x8*)&Qh[(size_t)q * E_ + c * 16 + hi * 8];

    f32x16 acc[2];
#pragma unroll
    for (int d = 0; d < 2; ++d)
#pragma unroll
        for (int r = 0; r < 16; ++r) acc[d][r] = 0.f;
    float m = -3e38f, mC = 0.f, l = 0.f;

    const int nw = (q0w + 95) >> 6;
    const int nt = (qt * 128 + 191) >> 6;

    const int kg0 = (l31 >> 3) * GRP + (l31 & 7) * 128;
    const int kg1 = ((32 + l31) >> 3) * GRP + (l31 & 7) * 128;
    const int ksw = (l31 & 7) << 4;

    auto stage = [&](int it, int buf) {
        const int kt0 = it * 64;
#pragma unroll
        for (int half = 0; half < 2; ++half) {
            const int grp = half * 4 + wv;
            const char* gk = (const char*)(Kh + (size_t)(kt0 + half * 32 + rstage) * E_) + cstage;
            __builtin_amdgcn_global_load_lds(gas(gk), las(&Kl[buf][0] + grp * GRP), 16, 0, 0);
            const char* gv = (const char*)Vh + (size_t)(half * 32 + rstage) * (S_ * 2) + (size_t)kt0 * 2 + cstage;
            __builtin_amdgcn_global_load_lds(gas(gv), las(&Vl[buf][0] + grp * GRP), 16, 0, 0);
        }
    };

    stage(0, 0);  // 4 calls in flight

    for (int it = 0; it < nt; ++it) {
        const int buf = it & 1;
        if (it + 1 < nt) {
            stage(it + 1, buf ^ 1);  // prefetch: in-flight 8
            VMW(4);                  // own stage(t) done; prefetch stays in flight
        } else {
            VMW(0);
        }
        __builtin_amdgcn_s_barrier();   // all waves' stage(t) visible
        __builtin_amdgcn_sched_barrier(0);
        if (it < nw) {
            const int kt0 = it * 64;
            const char* Kb_ = &Kl[buf][0];
            const char* Vb_ = &Vl[buf][0];
            f32x16 sc0, sc1;
#pragma unroll
            for (int r = 0; r < 16; ++r) { sc0[r] = 0.f; sc1[r] = 0.f; }
#pragma unroll
            for (int c = 0; c < 4; ++c) {
                bf16x8 kf0 = *(const bf16x8*)(Kb_ + kg0 + ((c * 32 + hi * 16) ^ ksw));
                bf16x8 kf1 = *(const bf16x8*)(Kb_ + kg1 + ((c * 32 + hi * 16) ^ ksw));
                sc0 = __builtin_amdgcn_mfma_f32_32x32x16_bf16(kf0, qf[c], sc0, 0, 0, 0);
                sc1 = __builtin_amdgcn_mfma_f32_32x32x16_bf16(kf1, qf[c], sc1, 0, 0, 0);
            }
            if (kt0 + 63 > q0w) {
                const int kb = kt0 + 4 * hi;
#pragma unroll
                for (int r = 0; r < 16; ++r) {
                    int key = kb + (r & 3) + 8 * (r >> 2);
                    sc0[r] = (key > q) ? -3e38f : sc0[r];
                    sc1[r] = (key + 32 > q) ? -3e38f : sc1[r];
                }
            }
            float tmx[8];
#pragma unroll
            for (int r = 0; r < 8; ++r)
                tmx[r] = fmaxf(fmaxf(sc0[2 * r], sc0[2 * r + 1]),
                               fmaxf(sc1[2 * r], sc1[2 * r + 1]));
            float tm = fmaxf(fmaxf(fmaxf(tmx[0], tmx[1]), fmaxf(tmx[2], tmx[3])),
                             fmaxf(fmaxf(tmx[4], tmx[5]), fmaxf(tmx[6], tmx[7])));
            tm = fmaxf(tm, __shfl_xor(tm, 32, 64));
            bool need = (tm > m + 16.0f);
            if (__ballot((int)need) != 0ull) {
                float mn = fmaxf(m, tm);
                float sf = exp2a((m - mn) * CEXP);
                m = mn; mC = mn * CEXP;
                l *= sf;
#pragma unroll
                for (int d = 0; d < 2; ++d)
#pragma unroll
                    for (int r = 0; r < 16; ++r) acc[d][r] *= sf;
            }
#pragma unroll
            for (int r = 0; r < 16; ++r) {
                sc0[r] = exp2a(fmaf(sc0[r], CEXP, -mC));
                sc1[r] = exp2a(fmaf(sc1[r], CEXP, -mC));
            }
            float s0 = 0.f, s1 = 0.f;
#pragma unroll
            for (int r = 0; r < 8; ++r) {
                s0 += sc0[2 * r] + sc0[2 * r + 1];
                s1 += sc1[2 * r] + sc1[2 * r + 1];
            }
            float ls = s0 + s1;
            ls += __shfl_xor(ls, 32, 64);
            l += ls;
            bf16x8 pf[4];
#pragma unroll
            for (int s = 0; s < 2; ++s) {
                const f32x16& p = s ? sc1 : sc0;
                unsigned a0 = cvtpk(p[0], p[1]),   a1 = cvtpk(p[2], p[3]);
                unsigned b0 = cvtpk(p[4], p[5]),   b1 = cvtpk(p[6], p[7]);
                unsigned a2 = cvtpk(p[8], p[9]),   a3 = cvtpk(p[10], p[11]);
                unsigned b2 = cvtpk(p[12], p[13]), b3 = cvtpk(p[14], p[15]);
                asm volatile("v_permlane32_swap_b32 %0, %1" : "+v"(a0), "+v"(b0));
                asm volatile("v_permlane32_swap_b32 %0, %1" : "+v"(a1), "+v"(b1));
                asm volatile("v_permlane32_swap_b32 %0, %1" : "+v"(a2), "+v"(b2));
                asm volatile("v_permlane32_swap_b32 %0, %1" : "+v"(a3), "+v"(b3));
                uint4v u1, u2;
                u1[0] = a0; u1[1] = a1; u1[2] = b0; u1[3] = b1;
                u2[0] = a2; u2[1] = a3; u2[2] = b2; u2[3] = b3;
                pf[s * 2] = __builtin_bit_cast(bf16x8, u1);
                pf[s * 2 + 1] = __builtin_bit_cast(bf16x8, u2);
            }
#pragma unroll
            for (int db = 0; db < 2; ++db) {
                const int row = db * 32 + l31;
                const int rsw = (row & 7) << 4;
                const char* vrow = Vb_ + (row >> 3) * GRP + (row & 7) * 128;
                bf16x8 v0 = *(const bf16x8*)(vrow + ((hi * 16) ^ rsw));
                bf16x8 v1 = *(const bf16x8*)(vrow + ((32 + hi * 16) ^ rsw));
                bf16x8 v2 = *(const bf16x8*)(vrow + ((64 + hi * 16) ^ rsw));
                bf16x8 v3 = *(const bf16x8*)(vrow + ((96 + hi * 16) ^ rsw));
                acc[db] = __builtin_amdgcn_mfma_f32_32x32x16_bf16(v0, pf[0], acc[db], 0, 0, 0);
                acc[db] = __builtin_amdgcn_mfma_f32_32x32x16_bf16(v1, pf[1], acc[db], 0, 0, 0);
                acc[db] = __builtin_amdgcn_mfma_f32_32x32x16_bf16(v2, pf[2], acc[db], 0, 0, 0);
                acc[db] = __builtin_amdgcn_mfma_f32_32x32x16_bf16(v3, pf[3], acc[db], 0, 0, 0);
            }
        }
        asm volatile("s_waitcnt lgkmcnt(0)" ::: "memory");
        __builtin_amdgcn_s_barrier();   // all reads of buf done before it's overwritten
    }

    float rl = __builtin_amdgcn_rcpf(l);
    short* orow = Ob + ((size_t)(bb * S_ + q)) * E_ + hh * 64;
#pragma unroll
    for (int db = 0; db < 2; ++db)
#pragma unroll
        for (int rb = 0; rb < 4; ++rb) {
            uint2v pk;
            pk[0] = cvtpk(acc[db][rb * 4 + 0] * rl, acc[db][rb * 4 + 1] * rl);
            pk[1] = cvtpk(acc[db][rb * 4 + 2] * rl, acc[db][rb * 4 + 3] * rl);
            *(uint2v*)&orow[db * 32 + rb * 8 + hi * 4] = pk;
        }
}

extern "C" void kernel_launch(void* const* d_in, const int* in_sizes, int n_in,
                              void* d_out, int out_size, void* d_ws, size_t ws_size,
                              hipStream_t stream) {
    const float* x      = (const float*)d_in[0];
    const float* w_attn = (const float*)d_in[1];
    const float* b_attn = (const float*)d_in[2];
    const float* w_out  = (const float*)d_in[3];
    const float* b_out  = (const float*)d_in[4];
    float* out = (float*)d_out;

    char* ws = (char*)d_ws;
    short* Xbf  = (short*)(ws);                       // 16 MB (reused as attn output)
    short* Wat  = (short*)(ws + (16ull << 20));       // 6 MB  [3072][1024]
    short* Wot  = (short*)(ws + (22ull << 20));       // 2 MB  [1024][1024]
    short* Qb   = (short*)(ws + (24ull << 20));       // 16 MB flat [8192][1024]
    short* Kb   = (short*)(ws + (40ull << 20));       // 16 MB flat [8192][1024]
    short* Vt   = (short*)(ws + (56ull << 20));       // 16 MB [B,H,D,S]
    short* Obuf = Xbf;

    prologue<<<6144, 256, 0, stream>>>(x, Xbf, w_attn, Wat, w_out, Wot);

    gemm_qkv<<<1024, 256, 0, stream>>>(Xbf, Wat, b_attn, Qb, Kb, Vt);

    attn_kernel<<<1024, 256, 0, stream>>>(Qb, Kb, Vt, Obuf);

    gemm_out<<<512, 256, 0, stream>>>(Obuf, Wot, b_out, out);
}